// Round 1
// baseline (2309.548 us; speedup 1.0000x reference)
//
#include <hip/hip_runtime.h>

// ---------------------------------------------------------------------------
// peepLSTM (B=512,S=256,H=768,E=6,C=10,V=3) — fp16 split MFMA, fence-free sync
//
//  r7 changes vs r6 (exchange-latency pipelining):
//   * Step split into two independent column-half phases (cols 0-15 / 16-31).
//     Phase-B MFMA overlaps phase-A epilogue (i-waves start B at S1);
//     A-exchange (spin+reload, i-waves) overlaps B-epilogue (f-waves);
//     B-exchange (spin+reload, f-waves) overlaps next step's phase-A MFMA
//     (i-waves run ahead after S3 — ldsA already refilled).
//   * 3 syncthreads/step (was 4); two barrier tokens/step: 2s+1 (A), 2s+2 (B).
//   * Per-phase zred/zbufP double buffers (A/B) — no intra-window races.
//  Wave map unchanged: w = pr*2+kh; pr: 0,1 = f rows 0-31/32-63; 2,3 = i rows.
// ---------------------------------------------------------------------------

typedef _Float16 f16x8 __attribute__((ext_vector_type(8)));
typedef _Float16 f16x4 __attribute__((ext_vector_type(4)));
typedef float    f32x4 __attribute__((ext_vector_type(4)));

#define Hdim  768
#define Bdim  512
#define Sdim  256
#define NSTEP 255
#define Edim  6
#define NCls  10
#define NGRP  16
#define NRB   12
#define GC    32
#define HB    64
#define NKK   24
#define NK2   12            // K-blocks per K-half
#define CSTR  776
#define XSTR  260
#define ZSTR2 17            // per-phase zbufP row stride (16 cols + pad)
#define PLANE (Bdim * Hdim)
#define SCL      4096.0f
#define SCL_INV  2.44140625e-4f

#define WP_FRAGS   (2 * NRB * 4 * NKK * 64)
#define WS_CBUF    0u
#define WS_HFIN    (2u * 2u * PLANE * 2u)
#define WS_BAR     (WS_HFIN + Bdim * Hdim * 4u)
#define WS_WPK     (WS_BAR + 4096u)
#define WS_BAR_BYTES (NGRP * 16u * 4u)

__device__ __forceinline__ float sigf(float z) { return 1.0f / (1.0f + __expf(-z)); }

__device__ __forceinline__ f32x4 mf(f16x8 a, f16x8 b, f32x4 c) {
    return __builtin_amdgcn_mfma_f32_16x16x32_f16(a, b, c, 0, 0, 0);
}

__device__ __forceinline__ void keepalive(f16x8& x) {
    asm volatile("" : "+v"(x));
}

// ---------------- prep: split W into fp16 hi / (lo*4096) fragment planes ----
__global__ void __launch_bounds__(256)
prep_w(const float* __restrict__ Wfh, const float* __restrict__ Wih,
       _Float16* __restrict__ wpk)
{
    const int fid  = blockIdx.x * 256 + threadIdx.x;
    const int lane = fid & 63;
    const int t1   = fid >> 6;
    const int kk   = t1 % NKK;
    const int gi   = t1 / NKK;            // (gate*12+rb)*4+sub
    const int sub  = gi & 3;
    const int t3   = gi >> 2;
    const int rb   = t3 % NRB;
    const int gate = t3 / NRB;
    const int q = lane >> 4, r = lane & 15;
    const int row = rb * 64 + sub * 16 + r;
    const int col = kk * 32 + q * 8;
    const float* src = (gate ? Wih : Wfh) + (size_t)row * Hdim + col;
    f16x8 hi, lo;
    #pragma unroll
    for (int j = 0; j < 8; ++j) {
        const float v = src[j];
        const _Float16 h = (_Float16)v;
        hi[j] = h;
        lo[j] = (_Float16)((v - (float)h) * SCL);
    }
    *(f16x8*)&wpk[(size_t)fid * 8] = hi;
    *(f16x8*)&wpk[((size_t)WP_FRAGS + fid) * 8] = lo;
}

// ---------------- main persistent kernel ------------------------------------
__global__ void __launch_bounds__(512, 1)
lstm_persist(const int* __restrict__ xk, const float* __restrict__ emb,
             const float* __restrict__ Wfx, const float* __restrict__ bfv,
             const float* __restrict__ Wix, const float* __restrict__ biv,
             const float* __restrict__ Wox, const float* __restrict__ Woh,
             const float* __restrict__ bov,
             const float* __restrict__ Wcx, const float* __restrict__ bcv,
             const float* __restrict__ cinit,
             const _Float16* __restrict__ wpk,
             _Float16* __restrict__ cbuf, float* __restrict__ hfin,
             unsigned int* __restrict__ bar)
{
    __shared__ __align__(16) _Float16 ldsH[GC * CSTR];        // 49,664 B
    __shared__ __align__(16) _Float16 ldsM[GC * CSTR];        // 49,664 B
    __shared__ __align__(16) float    tbl[3 * HB * 4];        //  3,072 B
    __shared__ __align__(16) float    zredA[4 * 2 * 64 * 4];  //  8,192 B
    __shared__ __align__(16) float    zredB[4 * 2 * 64 * 4];  //  8,192 B
    __shared__ __align__(16) float    zbufPA[2 * HB * ZSTR2]; //  8,704 B
    __shared__ __align__(16) float    zbufPB[2 * HB * ZSTR2]; //  8,704 B
    __shared__ __align__(4)  unsigned char xtok[GC * XSTR];   //  8,320 B
    __shared__ int s_flag;

    const int tid  = threadIdx.x;
    const int w    = tid >> 6;
    const int lane = tid & 63;
    const int q    = lane >> 4;
    const int r    = lane & 15;
    const int kh   = w & 1;             // K-half
    const int pr   = w >> 1;            // 0,1 = f rows 0-31/32-63 ; 2,3 = i
    const int gt   = pr >> 1;           // 0 = f, 1 = i
    const int rh   = pr & 1;            // 32-row half
    const int subp = rh * 2 + kh;       // epilogue 16-row tile (f-waves)
    const int bid  = blockIdx.x;
    const int g    = bid & 15;
    const int rb   = bid >> 4;
    const int blkh0 = rb * HB;
    const int gc0   = g * GC;
    const int hq0   = blkh0 + subp * 16 + q * 4;

    if (tid == 0) s_flag = 0;
    __syncthreads();
    if (tid < 256) {
        if (xk[(size_t)gc0 * Sdim + 2 * tid + 1] != 0) s_flag = 1;
    }
    if (tid < 3 * HB) {
        const int v  = tid >> 6;
        const int hl = tid & 63;
        const int hg = blkh0 + hl;
        float pf = bfv[hg], pi = biv[hg], po = bov[hg], pc = bcv[hg];
        #pragma unroll
        for (int e = 0; e < Edim; ++e) {
            const float ev = emb[v * Edim + e];
            pf += Wfx[hg * Edim + e] * ev;
            pi += Wix[hg * Edim + e] * ev;
            po += Wox[hg * Edim + e] * ev;
            pc += Wcx[hg * Edim + e] * ev;
        }
        float* t = &tbl[(v * HB + hl) * 4];
        t[0] = pf; t[1] = pi; t[2] = po; t[3] = sigf(pc);
    }
    __syncthreads();
    const int is64 = (s_flag == 0);

    {   // tokens -> LDS bytes
        const int col   = tid >> 4;
        const int sbase = (tid & 15) * 16;
        const size_t rowb = (size_t)(gc0 + col) * Sdim;
        for (int k2 = 0; k2 < 16; ++k2) {
            const int s0 = sbase + k2;
            const size_t idx = rowb + s0;
            xtok[col * XSTR + s0] = (unsigned char)xk[is64 ? (idx << 1) : idx];
        }
    }

    // persistent W fragments: 2 sub-tiles (rows rh*32 + s*16) x K-half kh
    f16x8 whi[2][NK2], wlo[2][NK2];
    #pragma unroll
    for (int s2 = 0; s2 < 2; ++s2) {
        const int gis = (gt * NRB + rb) * 4 + (rh * 2 + s2);
        #pragma unroll
        for (int k2 = 0; k2 < NK2; ++k2) {
            const size_t fo = ((size_t)(gis * NKK + kh * NK2 + k2) * 64 + lane) * 8;
            whi[s2][k2] = *(const f16x8*)&wpk[fo];
            wlo[s2][k2] = *(const f16x8*)&wpk[(size_t)WP_FRAGS * 8 + fo];
        }
    }
    #pragma unroll
    for (int s2 = 0; s2 < 2; ++s2)
        #pragma unroll
        for (int k2 = 0; k2 < NK2; ++k2) {
            keepalive(whi[s2][k2]);
            keepalive(wlo[s2][k2]);
        }

    // persistent fp32 c state for this wave's epilogue tile (f-waves use it)
    float cst[2][4];
    #pragma unroll
    for (int ct = 0; ct < 2; ++ct) {
        const int b = gc0 + ct * 16 + r;
        #pragma unroll
        for (int reg = 0; reg < 4; ++reg)
            cst[ct][reg] = cinit[(size_t)(hq0 + reg) * Bdim + b];
    }

    // step-0 LDS tiles from c_init
    for (int i = 0; i < 48; ++i) {
        const int idx = tid + i * 512;
        const int col = idx & 31, k = idx >> 5;
        const float v = cinit[(size_t)k * Bdim + gc0 + col];
        const _Float16 h = (_Float16)v;
        ldsH[col * CSTR + k] = h;
        ldsM[col * CSTR + k] = (_Float16)((v - (float)h) * SCL);
    }

    __syncthreads();                                  // prologue LDS ready

// ---- per-phase helper macros (capture locals) ------------------------------
#define MFMA_HALF(ROWOFF, AH0, AX0, AH1, AX1)                                  \
    {                                                                          \
        _Pragma("unroll")                                                      \
        for (int k2 = 0; k2 < NK2; ++k2) {                                     \
            const int lo = (kh * NK2 + k2) * 32 + q * 8;                       \
            const f16x8 bh = *(const f16x8*)&ldsH[((ROWOFF) + r) * CSTR + lo]; \
            const f16x8 bm = *(const f16x8*)&ldsM[((ROWOFF) + r) * CSTR + lo]; \
            AH0 = mf(whi[0][k2], bh, AH0);                                     \
            AX0 = mf(whi[0][k2], bm, AX0);                                     \
            AX0 = mf(wlo[0][k2], bh, AX0);                                     \
            AH1 = mf(whi[1][k2], bh, AH1);                                     \
            AX1 = mf(whi[1][k2], bm, AX1);                                     \
            AX1 = mf(wlo[1][k2], bh, AX1);                                     \
        }                                                                      \
    }

#define SEND_PART(ZRED, AH0, AX0, AH1, AX1)                                    \
    {                                                                          \
        f32x4* zr_ = (f32x4*)(ZRED);                                           \
        zr_[(w * 2 + 0) * 64 + lane] = kh ? AH0 : AH1;                         \
        zr_[(w * 2 + 1) * 64 + lane] = kh ? AX0 : AX1;                         \
    }

#define IPART(ZBUF, AH0, AX0, AH1, AX1)                                        \
    {                                                                          \
        float* zp_ = &(ZBUF)[kh * (HB * ZSTR2)];                               \
        _Pragma("unroll")                                                      \
        for (int s2 = 0; s2 < 2; ++s2) {                                       \
            const f32x4 h_ = s2 ? AH1 : AH0;                                   \
            const f32x4 x_ = s2 ? AX1 : AX0;                                   \
            _Pragma("unroll")                                                  \
            for (int reg = 0; reg < 4; ++reg) {                                \
                const int row_ = rh * 32 + s2 * 16 + q * 4 + reg;              \
                zp_[row_ * ZSTR2 + r] = h_[reg] + x_[reg] * SCL_INV;           \
            }                                                                  \
        }                                                                      \
    }

#define REDUCE_K(ZRED, KH_, KX_, ZF)                                           \
    {                                                                          \
        const f32x4* zr_ = (const f32x4*)(ZRED);                               \
        const int pw_ = w ^ 1;                                                 \
        const f32x4 pH_ = zr_[(pw_ * 2 + 0) * 64 + lane];                      \
        const f32x4 pX_ = zr_[(pw_ * 2 + 1) * 64 + lane];                      \
        _Pragma("unroll")                                                      \
        for (int reg = 0; reg < 4; ++reg)                                      \
            ZF[reg] = (KH_[reg] + pH_[reg]) + (KX_[reg] + pX_[reg]) * SCL_INV; \
    }

#define EPILOGUE_C(CT, ZF, ZBUF)                                               \
    {                                                                          \
        _Float16* cwH = cbuf + (size_t)(((s + 1) & 1) * 2) * PLANE;            \
        _Float16* cwM = cwH + PLANE;                                           \
        const int bl = (CT) * 16 + r;                                          \
        const int v  = xtok[bl * XSTR + s];                                    \
        const float* tb = &tbl[(v * HB + subp * 16 + q * 4) * 4];              \
        f16x4 cvh, cvm;                                                        \
        _Pragma("unroll")                                                      \
        for (int reg = 0; reg < 4; ++reg) {                                    \
            const int rowl = subp * 16 + q * 4 + reg;                          \
            const float zi = (ZBUF)[rowl * ZSTR2 + r]                          \
                           + (ZBUF)[HB * ZSTR2 + rowl * ZSTR2 + r];            \
            const float* tt = tb + reg * 4;                                    \
            const float fg = sigf(ZF[reg] + tt[0]);                            \
            const float ig = sigf(zi + tt[1]);                                 \
            const float cn = tt[3] * ig + cst[CT][reg] * fg;                   \
            cst[CT][reg] = cn;                                                 \
            const _Float16 ch = (_Float16)cn;                                  \
            cvh[reg] = ch;                                                     \
            cvm[reg] = (_Float16)((cn - (float)ch) * SCL);                     \
        }                                                                      \
        unsigned long long uh, um;                                             \
        __builtin_memcpy(&uh, &cvh, 8);                                        \
        __builtin_memcpy(&um, &cvm, 8);                                        \
        const size_t eo = (size_t)(gc0 + bl) * Hdim + hq0;                     \
        __hip_atomic_store((unsigned long long*)&cwH[eo], uh,                  \
                           __ATOMIC_RELAXED, __HIP_MEMORY_SCOPE_AGENT);        \
        __hip_atomic_store((unsigned long long*)&cwM[eo], um,                  \
                           __ATOMIC_RELAXED, __HIP_MEMORY_SCOPE_AGENT);        \
    }

#define SPIN(TGT)                                                              \
    {                                                                          \
        const unsigned tgt_ = (TGT);                                           \
        while (true) {                                                         \
            unsigned vv_ = tgt_;                                               \
            if (lane < NRB)                                                    \
                vv_ = __hip_atomic_load(&bar[g * 16 + lane],                   \
                                        __ATOMIC_RELAXED,                      \
                                        __HIP_MEMORY_SCOPE_AGENT);             \
            if (__all(vv_ >= tgt_)) break;                                     \
            __builtin_amdgcn_s_sleep(2);                                       \
        }                                                                      \
        asm volatile("" ::: "memory");                                         \
    }

#define LOAD_HALF(LCOL, JJ)                                                    \
    {                                                                          \
        const _Float16* crH = cbuf + (size_t)(((s + 1) & 1) * 2) * PLANE;      \
        const _Float16* crM = crH + PLANE;                                     \
        const size_t rowo = (size_t)(gc0 + (LCOL)) * Hdim;                     \
        unsigned long long th[12];                                             \
        _Pragma("unroll")                                                      \
        for (int i = 0; i < 12; ++i)                                           \
            th[i] = __hip_atomic_load(                                         \
                (unsigned long long*)&crH[rowo + ((JJ) + 16 * i) * 4],         \
                __ATOMIC_RELAXED, __HIP_MEMORY_SCOPE_AGENT);                   \
        _Pragma("unroll")                                                      \
        for (int i = 0; i < 12; ++i)                                           \
            *(unsigned long long*)&ldsH[(LCOL) * CSTR + ((JJ) + 16 * i) * 4] = th[i]; \
        unsigned long long tm[12];                                             \
        _Pragma("unroll")                                                      \
        for (int i = 0; i < 12; ++i)                                           \
            tm[i] = __hip_atomic_load(                                         \
                (unsigned long long*)&crM[rowo + ((JJ) + 16 * i) * 4],         \
                __ATOMIC_RELAXED, __HIP_MEMORY_SCOPE_AGENT);                   \
        _Pragma("unroll")                                                      \
        for (int i = 0; i < 12; ++i)                                           \
            *(unsigned long long*)&ldsM[(LCOL) * CSTR + ((JJ) + 16 * i) * 4] = tm[i]; \
    }

    for (int s = 0; s < NSTEP; ++s) {
        const bool last = (s == NSTEP - 1);

        // ---------------- Phase A: cols 0-15 --------------------------------
        f32x4 ah0 = {0,0,0,0}, ax0 = {0,0,0,0}, ah1 = {0,0,0,0}, ax1 = {0,0,0,0};
        MFMA_HALF(0, ah0, ax0, ah1, ax1);

        if (gt == 0) { SEND_PART(zredA, ah0, ax0, ah1, ax1); }
        else         { IPART(zbufPA, ah0, ax0, ah1, ax1); }

        __syncthreads();                              // S1: A partials ready

        // ---- Phase B MFMA; f-waves run epilogue-A first (i-waves feed the
        //      matrix pipe meanwhile — SIMD pairs f with i) ------------------
        f32x4 bh0v = {0,0,0,0}, bx0v = {0,0,0,0}, bh1v = {0,0,0,0}, bx1v = {0,0,0,0};
        float zfA[4];
        if (gt == 0) {
            const f32x4 kHa = kh ? ah1 : ah0;
            const f32x4 kXa = kh ? ax1 : ax0;
            REDUCE_K(zredA, kHa, kXa, zfA);
            if (!last) EPILOGUE_C(0, zfA, zbufPA);    // store c_A
            MFMA_HALF(16, bh0v, bx0v, bh1v, bx1v);
            SEND_PART(zredB, bh0v, bx0v, bh1v, bx1v);
        } else {
            MFMA_HALF(16, bh0v, bx0v, bh1v, bx1v);
            IPART(zbufPB, bh0v, bx0v, bh1v, bx1v);
        }

        asm volatile("s_waitcnt vmcnt(0)" ::: "memory");
        __syncthreads();                              // S2: B partials + c_A drained

        if (!last) {
            if (tid == 0)
                __hip_atomic_store(&bar[g * 16 + rb], (unsigned)(2 * s + 1),
                                   __ATOMIC_RELAXED, __HIP_MEMORY_SCOPE_AGENT);
            if (gt == 0) {
                // epilogue-B (overlaps i-waves' A-exchange below)
                const f32x4 kHb = kh ? bh1v : bh0v;
                const f32x4 kXb = kh ? bx1v : bx0v;
                float zfB[4];
                REDUCE_K(zredB, kHb, kXb, zfB);
                EPILOGUE_C(1, zfB, zbufPB);           // store c_B
            } else {
                // i-waves: A-exchange — spin barrier-A, reload cols 0-15
                SPIN((unsigned)(2 * s + 1));
                const int lt = tid - 256;
                LOAD_HALF(lt >> 4, lt & 15);
            }
            asm volatile("s_waitcnt vmcnt(0)" ::: "memory");
            __syncthreads();                          // S3: c_B drained, ldsA refilled
            if (tid == 0)
                __hip_atomic_store(&bar[g * 16 + rb], (unsigned)(2 * s + 2),
                                   __ATOMIC_RELAXED, __HIP_MEMORY_SCOPE_AGENT);
            if (gt == 0) {
                // f-waves: B-exchange — i-waves already running next phase-A
                SPIN((unsigned)(2 * s + 2));
                LOAD_HALF(16 + (tid >> 4), tid & 15);
            }
            // no trailing sync needed: ldsB reads happen after next S1
        } else {
            // ---------------- last step: h = tanh(c)*o ----------------------
            if (gt == 0) {
                const f32x4 kHb = kh ? bh1v : bh0v;
                const f32x4 kXb = kh ? bx1v : bx0v;
                float zfB[4];
                REDUCE_K(zredB, kHb, kXb, zfB);

                // full-K o-gate for this wave's 16 rows (both col-halves)
                f32x4 o0h = {0,0,0,0}, o0x = {0,0,0,0}, o1h = {0,0,0,0}, o1x = {0,0,0,0};
                const int arow = blkh0 + subp * 16 + r;
                #pragma unroll
                for (int kk = 0; kk < NKK; ++kk) {
                    const float* wp = Woh + (size_t)arow * Hdim + kk * 32 + q * 8;
                    f16x8 who;
                    #pragma unroll
                    for (int j = 0; j < 8; ++j) who[j] = (_Float16)wp[j];
                    const int lo = kk * 32 + q * 8;
                    const f16x8 bh0 = *(const f16x8*)&ldsH[ r       * CSTR + lo];
                    const f16x8 bm0 = *(const f16x8*)&ldsM[ r       * CSTR + lo];
                    const f16x8 bh1 = *(const f16x8*)&ldsH[(16 + r) * CSTR + lo];
                    const f16x8 bm1 = *(const f16x8*)&ldsM[(16 + r) * CSTR + lo];
                    o0h = mf(who, bh0, o0h);  o0x = mf(who, bm0, o0x);
                    o1h = mf(who, bh1, o1h);  o1x = mf(who, bm1, o1x);
                }
                #pragma unroll
                for (int ct = 0; ct < 2; ++ct) {
                    const int bl = ct * 16 + r;
                    const int v  = xtok[bl * XSTR + s];
                    const float* tb = &tbl[(v * HB + subp * 16 + q * 4) * 4];
                    const f32x4 zoh = ct ? o1h : o0h;
                    const f32x4 zox = ct ? o1x : o0x;
                    const float* zfp = ct ? zfB : zfA;
                    const float* zbp = ct ? zbufPB : zbufPA;
                    f32x4 hv;
                    #pragma unroll
                    for (int reg = 0; reg < 4; ++reg) {
                        const int rowl = subp * 16 + q * 4 + reg;
                        const float zi = zbp[rowl * ZSTR2 + r]
                                       + zbp[HB * ZSTR2 + rowl * ZSTR2 + r];
                        const float zo = zoh[reg] + zox[reg] * SCL_INV;
                        const float* tt = tb + reg * 4;
                        const float fg = sigf(zfp[reg] + tt[0]);
                        const float ig = sigf(zi + tt[1]);
                        const float og = sigf(zo + tt[2]);
                        const float cn = tt[3] * ig + cst[ct][reg] * fg;
                        const float e  = __expf(-2.0f * fabsf(cn));
                        const float th = __builtin_copysignf((1.0f - e) / (1.0f + e), cn);
                        hv[reg] = th * og;
                    }
                    *(f32x4*)&hfin[(size_t)(gc0 + bl) * Hdim + hq0] = hv;
                }
            }
        }
    }
}

__global__ void __launch_bounds__(64)
proj_kernel(const float* __restrict__ hfin, const float* __restrict__ Wph,
            const float* __restrict__ bpv, float* __restrict__ out)
{
    const int b = blockIdx.x;
    const int lane = threadIdx.x;
    float acc[NCls];
    #pragma unroll
    for (int c = 0; c < NCls; ++c) acc[c] = 0.f;
    const float* hb = &hfin[(size_t)b * Hdim];
    for (int i = 0; i < Hdim / 64; ++i) {
        const float hv = hb[lane + i * 64];
        #pragma unroll
        for (int c = 0; c < NCls; ++c)
            acc[c] += Wph[c * Hdim + lane + i * 64] * hv;
    }
    #pragma unroll
    for (int c = 0; c < NCls; ++c) {
        float v = acc[c];
        #pragma unroll
        for (int off = 32; off > 0; off >>= 1)
            v += __shfl_xor(v, off, 64);
        acc[c] = v + bpv[c];
    }
    float m = acc[0];
    #pragma unroll
    for (int c = 1; c < NCls; ++c) m = fmaxf(m, acc[c]);
    float ssum = 0.f;
    #pragma unroll
    for (int c = 0; c < NCls; ++c) ssum += __expf(acc[c] - m);
    const float lse = m + __logf(ssum);
    if (lane < NCls) out[b * NCls + lane] = acc[lane] - lse;
}

extern "C" void kernel_launch(void* const* d_in, const int* in_sizes, int n_in,
                              void* d_out, int out_size, void* d_ws, size_t ws_size,
                              hipStream_t stream)
{
    const int*   xk    = (const int*)d_in[0];
    const float* emb   = (const float*)d_in[1];
    const float* Wfx   = (const float*)d_in[2];
    const float* Wfh   = (const float*)d_in[3];
    const float* bfv   = (const float*)d_in[4];
    const float* Wix   = (const float*)d_in[5];
    const float* Wih   = (const float*)d_in[6];
    const float* biv   = (const float*)d_in[7];
    const float* Wox   = (const float*)d_in[8];
    const float* Woh   = (const float*)d_in[9];
    const float* bov   = (const float*)d_in[10];
    const float* Wcx   = (const float*)d_in[11];
    const float* bcv   = (const float*)d_in[12];
    const float* Wph   = (const float*)d_in[13];
    const float* bpv   = (const float*)d_in[14];
    const float* cinit = (const float*)d_in[15];

    char* ws = (char*)d_ws;
    _Float16*     cbuf = (_Float16*)(ws + WS_CBUF);
    float*        hfin = (float*)(ws + WS_HFIN);
    unsigned int* bar  = (unsigned int*)(ws + WS_BAR);
    _Float16*     wpk  = (_Float16*)(ws + WS_WPK);

    hipMemsetAsync(bar, 0, WS_BAR_BYTES, stream);

    prep_w<<<dim3(WP_FRAGS / 256), dim3(256), 0, stream>>>(Wfh, Wih, wpk);

    lstm_persist<<<dim3(NGRP * NRB), dim3(512), 0, stream>>>(
        xk, emb, Wfx, bfv, Wix, biv, Wox, Woh, bov, Wcx, bcv,
        cinit, wpk, cbuf, hfin, bar);

    proj_kernel<<<dim3(Bdim), dim3(64), 0, stream>>>(hfin, Wph, bpv, (float*)d_out);
}